// Round 1
// baseline (165.205 us; speedup 1.0000x reference)
//
#include <hip/hip_runtime.h>
#include <hip/hip_bf16.h>
#include <stdint.h>

typedef short vbf16x8 __attribute__((ext_vector_type(8)));
typedef float vf32x4 __attribute__((ext_vector_type(4)));
typedef unsigned short u16;

__device__ __forceinline__ float bf2f(u16 u) {
  union { unsigned int i; float f; } v; v.i = ((unsigned int)u) << 16; return v.f;
}
__device__ __forceinline__ u16 f2bf(float f) {
  union { float f; unsigned int i; } v; v.f = f;
  return (u16)((v.i + 0x7fffu + ((v.i >> 16) & 1u)) >> 16);
}
// async global->LDS, 16B per lane; LDS dst must be wave-uniform base (HW adds lane*16)
__device__ __forceinline__ void gld16(const void* g, void* l) {
  __builtin_amdgcn_global_load_lds((const __attribute__((address_space(1))) void*)g,
                                   (__attribute__((address_space(3))) void*)l, 16, 0, 0);
}

// ---- W fp32 [512][512] -> bf16
__global__ __launch_bounds__(256) void k_convw(const float* __restrict__ W, u16* __restrict__ Wb) {
  int i = blockIdx.x * 256 + threadIdx.x;   // one float4 each, 65536 total
  float4 x = ((const float4*)W)[i];
  ushort4 h;
  h.x = f2bf(x.x); h.y = f2bf(x.y); h.z = f2bf(x.z); h.w = f2bf(x.w);
  ((ushort4*)Wb)[i] = h;
}

// ---- input fp32 [8][2048][512] -> Abf bf16 (same layout) + Vt bf16 [8][512][2048]
__global__ __launch_bounds__(256) void k_prep(const float* __restrict__ in,
                                              u16* __restrict__ Abf, u16* __restrict__ Vt) {
  __shared__ u16 Ts[64][72];                 // 64x64 tile, +8 pad breaks bank conflicts
  const int tid = threadIdx.x;
  const int n0 = blockIdx.x * 64, d0 = blockIdx.y * 64, b = blockIdx.z;
  const float* src = in + ((long long)b * 2048 + n0) * 512 + d0;
#pragma unroll
  for (int j = 0; j < 4; ++j) {
    int chunk = tid + 256 * j;               // 1024 float4-chunks
    int r = chunk >> 4, c = (chunk & 15) * 4;
    float4 x = *(const float4*)(src + (long long)r * 512 + c);
    ushort4 h;
    h.x = f2bf(x.x); h.y = f2bf(x.y); h.z = f2bf(x.z); h.w = f2bf(x.w);
    *(ushort4*)(Abf + ((long long)b * 2048 + n0 + r) * 512 + d0 + c) = h;
    Ts[c + 0][r] = h.x; Ts[c + 1][r] = h.y; Ts[c + 2][r] = h.z; Ts[c + 3][r] = h.w;
  }
  __syncthreads();
#pragma unroll
  for (int j = 0; j < 2; ++j) {
    int chunk = tid + 256 * j;               // 512 16B-chunks
    int dr = chunk >> 3, c8 = (chunk & 7) * 8;
    vbf16x8 w = *(const vbf16x8*)&Ts[dr][c8];  // row stride 144B = 9*16 -> aligned
    *(vbf16x8*)(Vt + ((long long)b * 512 + d0 + dr) * 2048 + n0 + c8) = w;
  }
}

// ---- C[M][N] = A[M][K] @ Bt[N][K]^T (+bias). m97 structure: 128x128 tile, BK=32,
//      4 waves each 64x64 (4x4 frags of 16x16x32), global_load_lds staging.
template<bool OUTBF, bool BIAS>
__global__ __launch_bounds__(256) void k_gemm_bt(const u16* __restrict__ A,
                                                 const u16* __restrict__ Bt,
                                                 const float* __restrict__ bias,
                                                 void* __restrict__ Cout,
                                                 int M, int N, int K,
                                                 long long sA, long long sB, long long sC) {
  __shared__ u16 As[128 * 32];
  __shared__ u16 Bs[128 * 32];
  const int tid = threadIdx.x, lane = tid & 63, wv = tid >> 6;
  const int wr = wv >> 1, wc = wv & 1;
  const int brow = blockIdx.x * 128, bcol = blockIdx.y * 128;
  const long long z = blockIdx.z;
  const u16* gA0 = A + z * sA + (long long)brow * K;
  const u16* gB0 = Bt + z * sB + (long long)bcol * K;

  // staging map: chunk c covers rows [c*16, c*16+16), lane -> row c*16+lane/4, col (lane&3)*8
  const int rL = (wv * 2) * 16 + (lane >> 2);
  const int cL = (lane & 3) * 8;

  vf32x4 acc[4][4] = {};

  for (int k0 = 0; k0 < K; k0 += 32) {
    gld16(gA0 + (long long)rL * K + k0 + cL,        &As[(wv * 2) * 512]);
    gld16(gA0 + (long long)(rL + 16) * K + k0 + cL, &As[(wv * 2 + 1) * 512]);
    gld16(gB0 + (long long)rL * K + k0 + cL,        &Bs[(wv * 2) * 512]);
    gld16(gB0 + (long long)(rL + 16) * K + k0 + cL, &Bs[(wv * 2 + 1) * 512]);
    __syncthreads();                         // drains vmcnt before LDS reads
    vbf16x8 af[4], bf[4];
    const int ra = (lane & 15) * 32 + (lane >> 4) * 8;
#pragma unroll
    for (int t = 0; t < 4; ++t) {
      af[t] = *(const vbf16x8*)&As[(wr * 64 + t * 16) * 32 + ra];
      bf[t] = *(const vbf16x8*)&Bs[(wc * 64 + t * 16) * 32 + ra];
    }
#pragma unroll
    for (int i = 0; i < 4; ++i)
#pragma unroll
      for (int j = 0; j < 4; ++j)
        acc[i][j] = __builtin_amdgcn_mfma_f32_16x16x32_bf16(af[i], bf[j], acc[i][j], 0, 0, 0);
    __syncthreads();
  }

  const long long zc = z * sC;
#pragma unroll
  for (int i = 0; i < 4; ++i) {
    const int row0 = brow + wr * 64 + i * 16 + (lane >> 4) * 4;  // C/D: col=lane&15, row=(lane>>4)*4+r
#pragma unroll
    for (int j = 0; j < 4; ++j) {
      const int col = bcol + wc * 64 + j * 16 + (lane & 15);
      const float bv = BIAS ? bias[col] : 0.0f;
#pragma unroll
      for (int r = 0; r < 4; ++r) {
        const float v = acc[i][j][r] + bv;
        const long long off = zc + (long long)(row0 + r) * N + col;
        if (OUTBF) ((u16*)Cout)[off] = f2bf(v);
        else       ((float*)Cout)[off] = v;
      }
    }
  }
}

// ---- row softmax in-place on bf16 [rows][2048]; one block per row
__global__ __launch_bounds__(256) void k_softmax(u16* __restrict__ P) {
  const long long row = blockIdx.x;
  u16* p = P + row * 2048;
  const int tid = threadIdx.x, lane = tid & 63, wv = tid >> 6;
  vbf16x8 v = ((const vbf16x8*)p)[tid];      // 8 bf16 per thread
  float f[8];
#pragma unroll
  for (int j = 0; j < 8; ++j) f[j] = bf2f((u16)v[j]);
  float m = f[0];
#pragma unroll
  for (int j = 1; j < 8; ++j) m = fmaxf(m, f[j]);
  for (int o = 1; o < 64; o <<= 1) m = fmaxf(m, __shfl_xor(m, o));
  __shared__ float redm[4], reds[4];
  if (lane == 0) redm[wv] = m;
  __syncthreads();
  m = fmaxf(fmaxf(redm[0], redm[1]), fmaxf(redm[2], redm[3]));
  float s = 0.0f;
#pragma unroll
  for (int j = 0; j < 8; ++j) { f[j] = __expf(f[j] - m); s += f[j]; }
  for (int o = 1; o < 64; o <<= 1) s += __shfl_xor(s, o);
  if (lane == 0) reds[wv] = s;
  __syncthreads();
  const float inv = 1.0f / (reds[0] + reds[1] + reds[2] + reds[3]);
#pragma unroll
  for (int j = 0; j < 8; ++j) v[j] = (short)f2bf(f[j] * inv);
  ((vbf16x8*)p)[tid] = v;
}

extern "C" void kernel_launch(void* const* d_in, const int* in_sizes, int n_in,
                              void* d_out, int out_size, void* d_ws, size_t ws_size,
                              hipStream_t stream) {
  const float* input = (const float*)d_in[0];   // [8][2048][512] f32
  const float* W     = (const float*)d_in[1];   // [512][512] f32
  const float* bias  = (const float*)d_in[2];   // [512] f32
  float* out = (float*)d_out;                   // [8][2048][512] f32

  char* ws = (char*)d_ws;
  // layout (96 MiB total): Xbf | Vt | P (Abf and Wb alias the head of P:
  // their lifetime ends before S-GEMM writes P)
  u16* Xbf = (u16*)(ws);                                  // 16 MiB
  u16* Vt  = (u16*)(ws + 16777216);                       // 16 MiB
  u16* P   = (u16*)(ws + 2LL * 16777216);                 // 64 MiB
  u16* Abf = (u16*)(ws + 2LL * 16777216);                 // alias (first 16 MiB of P)
  u16* Wb  = (u16*)(ws + 3LL * 16777216);                 // alias (0.5 MiB inside P)

  // 1) W -> bf16
  k_convw<<<256, 256, 0, stream>>>(W, Wb);
  // 2) input -> bf16 + transposed copy Vt[b][d][n]
  k_prep<<<dim3(32, 8, 8), 256, 0, stream>>>(input, Abf, Vt);
  // 3) X = input @ W^T + b   (M=16384, N=512, K=512) -> bf16
  k_gemm_bt<true, true><<<dim3(128, 4, 1), 256, 0, stream>>>(
      Abf, Wb, bias, Xbf, 16384, 512, 512, 0, 0, 0);
  // 4) S = X @ X^T per batch (M=N=2048, K=512) -> bf16 (into P buffer)
  k_gemm_bt<true, false><<<dim3(16, 16, 8), 256, 0, stream>>>(
      Xbf, Xbf, nullptr, P, 2048, 2048, 512,
      2048LL * 512, 2048LL * 512, 2048LL * 2048);
  // 5) softmax rows in place
  k_softmax<<<16384, 256, 0, stream>>>(P);
  // 6) out = P @ Vt^T per batch (M=2048, N=512, K=2048) -> f32
  k_gemm_bt<false, false><<<dim3(16, 4, 8), 256, 0, stream>>>(
      P, Vt, nullptr, out, 2048, 512, 2048,
      2048LL * 2048, 512LL * 2048, 2048LL * 512);
}

// Round 3
// 135.827 us; speedup vs baseline: 1.2163x; 1.2163x over previous
//
#include <hip/hip_runtime.h>
#include <hip/hip_bf16.h>
#include <stdint.h>

typedef short vbf16x8 __attribute__((ext_vector_type(8)));
typedef float vf32x4 __attribute__((ext_vector_type(4)));
typedef unsigned short u16;

__device__ __forceinline__ float bf2f(u16 u) {
  union { unsigned int i; float f; } v; v.i = ((unsigned int)u) << 16; return v.f;
}
__device__ __forceinline__ u16 f2bf(float f) {
  union { float f; unsigned int i; } v; v.f = f;
  return (u16)((v.i + 0x7fffu + ((v.i >> 16) & 1u)) >> 16);
}
__device__ __forceinline__ void gld16(const void* g, void* l) {
  __builtin_amdgcn_global_load_lds((const __attribute__((address_space(1))) void*)g,
                                   (__attribute__((address_space(3))) void*)l, 16, 0, 0);
}
template<int N> __device__ __forceinline__ void wait_vmcnt() {
  asm volatile("s_waitcnt vmcnt(%0)" :: "n"(N) : "memory");
}
__device__ __forceinline__ vbf16x8 ldsv(const u16* p) { return *(const vbf16x8*)p; }

// ---- W fp32 [512][512] -> bf16
__global__ __launch_bounds__(256) void k_convw(const float* __restrict__ W, u16* __restrict__ Wb) {
  int i = blockIdx.x * 256 + threadIdx.x;
  float4 x = ((const float4*)W)[i];
  ushort4 h;
  h.x = f2bf(x.x); h.y = f2bf(x.y); h.z = f2bf(x.z); h.w = f2bf(x.w);
  ((ushort4*)Wb)[i] = h;
}

// ---- input fp32 [8][2048][512] -> Abf bf16 (same layout) + Vt bf16 [8][512][2048]
__global__ __launch_bounds__(256) void k_prep(const float* __restrict__ in,
                                              u16* __restrict__ Abf, u16* __restrict__ Vt) {
  __shared__ u16 Ts[64][72];
  const int tid = threadIdx.x;
  const int n0 = blockIdx.x * 64, d0 = blockIdx.y * 64, b = blockIdx.z;
  const float* src = in + ((long long)b * 2048 + n0) * 512 + d0;
#pragma unroll
  for (int j = 0; j < 4; ++j) {
    int chunk = tid + 256 * j;
    int r = chunk >> 4, c = (chunk & 15) * 4;
    float4 x = *(const float4*)(src + (long long)r * 512 + c);
    ushort4 h;
    h.x = f2bf(x.x); h.y = f2bf(x.y); h.z = f2bf(x.z); h.w = f2bf(x.w);
    *(ushort4*)(Abf + ((long long)b * 2048 + n0 + r) * 512 + d0 + c) = h;
    Ts[c + 0][r] = h.x; Ts[c + 1][r] = h.y; Ts[c + 2][r] = h.z; Ts[c + 3][r] = h.w;
  }
  __syncthreads();
#pragma unroll
  for (int j = 0; j < 2; ++j) {
    int chunk = tid + 256 * j;
    int dr = chunk >> 3, c8 = (chunk & 7) * 8;
    vbf16x8 w = *(const vbf16x8*)&Ts[dr][c8];
    *(vbf16x8*)(Vt + ((long long)b * 512 + d0 + dr) * 2048 + n0 + c8) = w;
  }
}

// ================= 256xBN 8-phase GEMM (C = A @ Bt^T), BK=64 ==================
// 512 threads = 8 waves (2 Mrows x 4 Ncols); per-wave 128 x (16*NF).
// LDS per operand: [buf][kh][rows][32] u16, kh = 32-wide K-half.
// XOR slot swizzle on 16B slots: physical_slot = logical_slot ^ ((row>>1)&3);
// global_load_lds writes linearly, so the stager loads from the pre-swizzled
// global column instead (both-sides-or-neither, rule m173/m231).
template<int NF, int PART>
__device__ __forceinline__ void stage_part(int tile, int NT, const u16* gA, const u16* gB,
                                           u16* As, u16* Bs, int rA, int colsw, int K, int wv) {
  if (tile >= NT) return;
  constexpr int kh = PART >> 1;
  constexpr int isB = PART & 1;
  const int buf = tile & 1;
  const int k0 = tile * 64 + kh * 32;
  if constexpr (!isB) {
    const u16* src = gA + (long long)rA * K + k0 + colsw;
    u16* dst = As + (buf * 2 + kh) * 8192 + wv * 512;
    gld16(src, dst);
    gld16(src + 128LL * K, dst + 4096);
  } else {
    constexpr int BN = 64 * NF;
    const u16* src = gB + (long long)rA * K + k0 + colsw;
    u16* dst = Bs + (buf * 2 + kh) * (BN * 32) + wv * 512;
    gld16(src, dst);
    if constexpr (NF == 4) gld16(src + 128LL * K, dst + 4096);
  }
}

template<int NF, bool OUTBF, bool BIAS>
__global__ __launch_bounds__(512, 2) void k_gemm8(const u16* __restrict__ A,
                                                  const u16* __restrict__ Bt,
                                                  const float* __restrict__ bias,
                                                  void* __restrict__ Cout,
                                                  int M, int N, int K,
                                                  long long sA, long long sB, long long sC) {
  static_assert(NF == 2 || NF == 4, "NF");
  constexpr int BN = 64 * NF;
  constexpr int LB = NF / 2;               // gld16 rounds per B half-tile
  constexpr int V_MAIN = 4 + LB;           // newest 3 half-tiles outstanding
  constexpr int V_LAST = 2 + LB;           // last tile, phase 0
  __shared__ __align__(16) u16 As[2 * 2 * 256 * 32];
  __shared__ __align__(16) u16 Bs[2 * 2 * BN * 32];

  const int tid = threadIdx.x, lane = tid & 63, wv = tid >> 6;
  const int wr = wv >> 2, wc = wv & 3;
  const int brow = blockIdx.x * 256, bcol = blockIdx.y * BN;
  const long long z = blockIdx.z;
  const u16* gA = A + z * sA + (long long)brow * K;
  const u16* gB = Bt + z * sB + (long long)bcol * K;
  const int NT = K >> 6;

  // staging per-lane constants (linear LDS write: row = wv*16 + lane/4, slot = lane&3)
  const int rA = wv * 16 + (lane >> 2);
  const int colsw = (((lane & 3) ^ ((lane >> 3) & 3)) << 3);  // pre-swizzled global col (u16)

  // read-side per-lane constants: row = frag*16 + (lane&15), logical slot = lane>>4
  const int slotp = ((lane >> 4) ^ (((lane & 15) >> 1) & 3));
  const int rdoff = (lane & 15) * 32 + slotp * 8;

  vf32x4 acc[8][NF] = {};

  // prologue: tile0 all 4 halves + tile1 A-kh0  (lead-5 half-tile stream)
  stage_part<NF, 0>(0, NT, gA, gB, As, Bs, rA, colsw, K, wv);
  stage_part<NF, 1>(0, NT, gA, gB, As, Bs, rA, colsw, K, wv);
  stage_part<NF, 2>(0, NT, gA, gB, As, Bs, rA, colsw, K, wv);
  stage_part<NF, 3>(0, NT, gA, gB, As, Bs, rA, colsw, K, wv);
  stage_part<NF, 0>(1, NT, gA, gB, As, Bs, rA, colsw, K, wv);

  for (int t = 0; t < NT; ++t) {
    const int buf = t & 1;
    const u16* Ak0 = As + (buf * 2 + 0) * 8192 + wr * 4096 + rdoff;
    const u16* Ak1 = As + (buf * 2 + 1) * 8192 + wr * 4096 + rdoff;
    const u16* Bk0 = Bs + (buf * 2 + 0) * (BN * 32) + wc * (16 * NF) * 32 + rdoff;
    const u16* Bk1 = Bs + (buf * 2 + 1) * (BN * 32) + wc * (16 * NF) * 32 + rdoff;
    vbf16x8 afr[4], bfr[NF];

    // ---- phase 0: gate kh0, frags m0-3 x all n, kh0
    if (t < NT - 1) wait_vmcnt<V_MAIN>(); else wait_vmcnt<V_LAST>();
    __builtin_amdgcn_sched_barrier(0);
    __builtin_amdgcn_s_barrier();
    __builtin_amdgcn_sched_barrier(0);
#pragma unroll
    for (int n = 0; n < NF; ++n) bfr[n] = ldsv(Bk0 + n * 512);
#pragma unroll
    for (int i = 0; i < 4; ++i) afr[i] = ldsv(Ak0 + i * 512);
    stage_part<NF, 1>(t + 1, NT, gA, gB, As, Bs, rA, colsw, K, wv);
    __builtin_amdgcn_s_setprio(1);
#pragma unroll
    for (int i = 0; i < 4; ++i)
#pragma unroll
      for (int n = 0; n < NF; ++n)
        acc[i][n] = __builtin_amdgcn_mfma_f32_16x16x32_bf16(afr[i], bfr[n], acc[i][n], 0, 0, 0);
    __builtin_amdgcn_s_setprio(0);

    // ---- phase 1: frags m4-7, kh0
#pragma unroll
    for (int i = 0; i < 4; ++i) afr[i] = ldsv(Ak0 + (4 + i) * 512);
    stage_part<NF, 2>(t + 1, NT, gA, gB, As, Bs, rA, colsw, K, wv);
    __builtin_amdgcn_s_setprio(1);
#pragma unroll
    for (int i = 0; i < 4; ++i)
#pragma unroll
      for (int n = 0; n < NF; ++n)
        acc[4 + i][n] = __builtin_amdgcn_mfma_f32_16x16x32_bf16(afr[i], bfr[n], acc[4 + i][n], 0, 0, 0);
    __builtin_amdgcn_s_setprio(0);

    // ---- phase 2: gate kh1, frags m0-3, kh1
    if (t < NT - 1) wait_vmcnt<V_MAIN>(); else wait_vmcnt<0>();
    __builtin_amdgcn_sched_barrier(0);
    __builtin_amdgcn_s_barrier();
    __builtin_amdgcn_sched_barrier(0);
#pragma unroll
    for (int n = 0; n < NF; ++n) bfr[n] = ldsv(Bk1 + n * 512);
#pragma unroll
    for (int i = 0; i < 4; ++i) afr[i] = ldsv(Ak1 + i * 512);
    stage_part<NF, 3>(t + 1, NT, gA, gB, As, Bs, rA, colsw, K, wv);
    __builtin_amdgcn_s_setprio(1);
#pragma unroll
    for (int i = 0; i < 4; ++i)
#pragma unroll
      for (int n = 0; n < NF; ++n)
        acc[i][n] = __builtin_amdgcn_mfma_f32_16x16x32_bf16(afr[i], bfr[n], acc[i][n], 0, 0, 0);
    __builtin_amdgcn_s_setprio(0);

    // ---- phase 3: frags m4-7, kh1
#pragma unroll
    for (int i = 0; i < 4; ++i) afr[i] = ldsv(Ak1 + (4 + i) * 512);
    stage_part<NF, 0>(t + 2, NT, gA, gB, As, Bs, rA, colsw, K, wv);
    __builtin_amdgcn_s_setprio(1);
#pragma unroll
    for (int i = 0; i < 4; ++i)
#pragma unroll
      for (int n = 0; n < NF; ++n)
        acc[4 + i][n] = __builtin_amdgcn_mfma_f32_16x16x32_bf16(afr[i], bfr[n], acc[4 + i][n], 0, 0, 0);
    __builtin_amdgcn_s_setprio(0);
  }

  // ---- epilogue: C/D layout col=lane&15, row=(lane>>4)*4+r
  const long long zc = z * sC;
#pragma unroll
  for (int m = 0; m < 8; ++m) {
    const int row0 = brow + wr * 128 + m * 16 + (lane >> 4) * 4;
#pragma unroll
    for (int n = 0; n < NF; ++n) {
      const int col = bcol + wc * (16 * NF) + n * 16 + (lane & 15);
      const float bv = BIAS ? bias[col] : 0.0f;
#pragma unroll
      for (int r = 0; r < 4; ++r) {
        const float v = acc[m][n][r] + bv;
        const long long off = zc + (long long)(row0 + r) * N + col;
        if (OUTBF) ((u16*)Cout)[off] = f2bf(v);
        else       ((float*)Cout)[off] = v;
      }
    }
  }
}

// ---- row softmax in-place on bf16 [rows][2048]; one block per row
__global__ __launch_bounds__(256) void k_softmax(u16* __restrict__ P) {
  const long long row = blockIdx.x;
  u16* p = P + row * 2048;
  const int tid = threadIdx.x, lane = tid & 63, wv = tid >> 6;
  vbf16x8 v = ((const vbf16x8*)p)[tid];
  float f[8];
#pragma unroll
  for (int j = 0; j < 8; ++j) f[j] = bf2f((u16)v[j]);
  float m = f[0];
#pragma unroll
  for (int j = 1; j < 8; ++j) m = fmaxf(m, f[j]);
  for (int o = 1; o < 64; o <<= 1) m = fmaxf(m, __shfl_xor(m, o));
  __shared__ float redm[4], reds[4];
  if (lane == 0) redm[wv] = m;
  __syncthreads();
  m = fmaxf(fmaxf(redm[0], redm[1]), fmaxf(redm[2], redm[3]));
  float s = 0.0f;
#pragma unroll
  for (int j = 0; j < 8; ++j) { f[j] = __expf(f[j] - m); s += f[j]; }
  for (int o = 1; o < 64; o <<= 1) s += __shfl_xor(s, o);
  if (lane == 0) reds[wv] = s;
  __syncthreads();
  const float inv = 1.0f / (reds[0] + reds[1] + reds[2] + reds[3]);
#pragma unroll
  for (int j = 0; j < 8; ++j) v[j] = (short)f2bf(f[j] * inv);
  ((vbf16x8*)p)[tid] = v;
}

extern "C" void kernel_launch(void* const* d_in, const int* in_sizes, int n_in,
                              void* d_out, int out_size, void* d_ws, size_t ws_size,
                              hipStream_t stream) {
  const float* input = (const float*)d_in[0];   // [8][2048][512] f32
  const float* W     = (const float*)d_in[1];   // [512][512] f32
  const float* bias  = (const float*)d_in[2];   // [512] f32
  float* out = (float*)d_out;                   // [8][2048][512] f32

  char* ws = (char*)d_ws;
  u16* Xbf = (u16*)(ws);                        // 16 MiB
  u16* Vt  = (u16*)(ws + 16777216);             // 16 MiB
  u16* P   = (u16*)(ws + 2LL * 16777216);       // 64 MiB
  u16* Abf = (u16*)(ws + 2LL * 16777216);       // alias (first 16 MiB of P)
  u16* Wb  = (u16*)(ws + 3LL * 16777216);       // alias (0.5 MiB inside P)

  // 1) W -> bf16
  k_convw<<<256, 256, 0, stream>>>(W, Wb);
  // 2) input -> bf16 + transposed copy Vt[b][d][n]
  k_prep<<<dim3(32, 8, 8), 256, 0, stream>>>(input, Abf, Vt);
  // 3) X = input @ W^T + b   (16384x512x512) -> bf16   [256 blocks]
  k_gemm8<2, true, true><<<dim3(64, 4, 1), 512, 0, stream>>>(
      Abf, Wb, bias, Xbf, 16384, 512, 512, 0, 0, 0);
  // 4) S = X @ X^T per batch (2048x2048x512) -> bf16   [512 blocks]
  k_gemm8<4, true, false><<<dim3(8, 8, 8), 512, 0, stream>>>(
      Xbf, Xbf, nullptr, P, 2048, 2048, 512,
      2048LL * 512, 2048LL * 512, 2048LL * 2048);
  // 5) softmax rows in place
  k_softmax<<<16384, 256, 0, stream>>>(P);
  // 6) out = P @ Vt^T per batch (2048x512x2048) -> f32 [256 blocks]
  k_gemm8<2, false, false><<<dim3(8, 4, 8), 512, 0, stream>>>(
      P, Vt, nullptr, out, 2048, 512, 2048,
      2048LL * 2048, 512LL * 2048, 2048LL * 512);
}

// Round 4
// 133.371 us; speedup vs baseline: 1.2387x; 1.0184x over previous
//
#include <hip/hip_runtime.h>
#include <hip/hip_bf16.h>
#include <stdint.h>

typedef short vbf16x8 __attribute__((ext_vector_type(8)));
typedef float vf32x4 __attribute__((ext_vector_type(4)));
typedef unsigned short u16;

__device__ __forceinline__ float bf2f(u16 u) {
  union { unsigned int i; float f; } v; v.i = ((unsigned int)u) << 16; return v.f;
}
__device__ __forceinline__ u16 f2bf(float f) {
  union { float f; unsigned int i; } v; v.f = f;
  return (u16)((v.i + 0x7fffu + ((v.i >> 16) & 1u)) >> 16);
}
__device__ __forceinline__ void gld16(const void* g, void* l) {
  __builtin_amdgcn_global_load_lds((const __attribute__((address_space(1))) void*)g,
                                   (__attribute__((address_space(3))) void*)l, 16, 0, 0);
}
template<int N> __device__ __forceinline__ void wait_vmcnt() {
  asm volatile("s_waitcnt vmcnt(%0)" :: "n"(N) : "memory");
}
__device__ __forceinline__ vbf16x8 ldsv(const u16* p) { return *(const vbf16x8*)p; }

// ---- W fp32 [512][512] -> bf16
__global__ __launch_bounds__(256) void k_convw(const float* __restrict__ W, u16* __restrict__ Wb) {
  int i = blockIdx.x * 256 + threadIdx.x;
  float4 x = ((const float4*)W)[i];
  ushort4 h;
  h.x = f2bf(x.x); h.y = f2bf(x.y); h.z = f2bf(x.z); h.w = f2bf(x.w);
  ((ushort4*)Wb)[i] = h;
}

// ---- input fp32 [8][2048][512] -> Abf bf16 (same layout) + Vt bf16 [8][512][2048]
__global__ __launch_bounds__(256) void k_prep(const float* __restrict__ in,
                                              u16* __restrict__ Abf, u16* __restrict__ Vt) {
  __shared__ u16 Ts[64][72];
  const int tid = threadIdx.x;
  const int n0 = blockIdx.x * 64, d0 = blockIdx.y * 64, b = blockIdx.z;
  const float* src = in + ((long long)b * 2048 + n0) * 512 + d0;
#pragma unroll
  for (int j = 0; j < 4; ++j) {
    int chunk = tid + 256 * j;
    int r = chunk >> 4, c = (chunk & 15) * 4;
    float4 x = *(const float4*)(src + (long long)r * 512 + c);
    ushort4 h;
    h.x = f2bf(x.x); h.y = f2bf(x.y); h.z = f2bf(x.z); h.w = f2bf(x.w);
    *(ushort4*)(Abf + ((long long)b * 2048 + n0 + r) * 512 + d0 + c) = h;
    Ts[c + 0][r] = h.x; Ts[c + 1][r] = h.y; Ts[c + 2][r] = h.z; Ts[c + 3][r] = h.w;
  }
  __syncthreads();
#pragma unroll
  for (int j = 0; j < 2; ++j) {
    int chunk = tid + 256 * j;
    int dr = chunk >> 3, c8 = (chunk & 7) * 8;
    vbf16x8 w = *(const vbf16x8*)&Ts[dr][c8];
    *(vbf16x8*)(Vt + ((long long)b * 512 + d0 + dr) * 2048 + n0 + c8) = w;
  }
}

// ================= 256xBN 8-phase GEMM (C = A @ Bt^T), BK=64 ==================
// 512 threads = 8 waves (2 Mrows x 4 Ncols); per-wave 128 x (16*NF).
// XOR slot swizzle on 16B slots; global_load_lds writes linearly, so the
// stager loads from the pre-swizzled global column (both-sides rule).
// MAP (T1, XCD-aware 1-D grid decode; XCD = lin%8 round-robin):
//   MAP=0 (S-GEMM, 512 wg):  z=xcd, idx=lin>>3: brow=idx>>3, bcol=idx&7  -> 1 batch per XCD
//   MAP=1 (GEMM1, 256 wg):   z=0,   idx=lin>>3: brow=xcd*8+(idx>>2), bcol=idx&3
//   MAP=2 (PV,    256 wg):   z=xcd, idx=lin>>3: brow=idx>>2, bcol=idx&3
template<int NF, int PART>
__device__ __forceinline__ void stage_part(int tile, int NT, const u16* gA, const u16* gB,
                                           u16* As, u16* Bs, int rA, int colsw, int K, int wv) {
  if (tile >= NT) return;
  constexpr int kh = PART >> 1;
  constexpr int isB = PART & 1;
  const int buf = tile & 1;
  const int k0 = tile * 64 + kh * 32;
  if constexpr (!isB) {
    const u16* src = gA + (long long)rA * K + k0 + colsw;
    u16* dst = As + (buf * 2 + kh) * 8192 + wv * 512;
    gld16(src, dst);
    gld16(src + 128LL * K, dst + 4096);
  } else {
    constexpr int BN = 64 * NF;
    const u16* src = gB + (long long)rA * K + k0 + colsw;
    u16* dst = Bs + (buf * 2 + kh) * (BN * 32) + wv * 512;
    gld16(src, dst);
    if constexpr (NF == 4) gld16(src + 128LL * K, dst + 4096);
  }
}

template<int NF, bool OUTBF, bool BIAS, int MAP>
__global__ __launch_bounds__(512, 2) void k_gemm8(const u16* __restrict__ A,
                                                  const u16* __restrict__ Bt,
                                                  const float* __restrict__ bias,
                                                  void* __restrict__ Cout,
                                                  int M, int N, int K,
                                                  long long sA, long long sB, long long sC) {
  static_assert(NF == 2 || NF == 4, "NF");
  constexpr int BN = 64 * NF;
  constexpr int LB = NF / 2;               // gld16 rounds per B half-tile
  constexpr int V_MAIN = 4 + LB;           // newest 3 half-tile-groups outstanding
  constexpr int V_LAST = 2 + LB;           // last tile, phase 0
  __shared__ __align__(16) u16 As[2 * 2 * 256 * 32];
  __shared__ __align__(16) u16 Bs[2 * 2 * BN * 32];

  const int tid = threadIdx.x, lane = tid & 63, wv = tid >> 6;
  const int wr = wv >> 2, wc = wv & 3;

  // T1: XCD-aware decode from 1-D grid
  const int lin = blockIdx.x;
  const int xcd = lin & 7, idx = lin >> 3;
  int zb, browi, bcoli;
  if constexpr (MAP == 0) { zb = xcd; browi = idx >> 3; bcoli = idx & 7; }
  else if constexpr (MAP == 1) { zb = 0; browi = xcd * 8 + (idx >> 2); bcoli = idx & 3; }
  else { zb = xcd; browi = idx >> 2; bcoli = idx & 3; }
  const int brow = browi * 256, bcol = bcoli * BN;
  const long long z = zb;

  const u16* gA = A + z * sA + (long long)brow * K;
  const u16* gB = Bt + z * sB + (long long)bcol * K;
  const int NT = K >> 6;

  // staging per-lane constants (linear LDS write: row = wv*16 + lane/4, slot = lane&3)
  const int rA = wv * 16 + (lane >> 2);
  const int colsw = (((lane & 3) ^ ((lane >> 3) & 3)) << 3);  // pre-swizzled global col (u16)

  // read-side per-lane constants: row = frag*16 + (lane&15), logical slot = lane>>4
  const int slotp = ((lane >> 4) ^ (((lane & 15) >> 1) & 3));
  const int rdoff = (lane & 15) * 32 + slotp * 8;

  vf32x4 acc[8][NF] = {};

  // prologue: tile0 all 4 halves + tile1 A-kh0 (lead-5 half-tile stream)
  stage_part<NF, 0>(0, NT, gA, gB, As, Bs, rA, colsw, K, wv);
  stage_part<NF, 1>(0, NT, gA, gB, As, Bs, rA, colsw, K, wv);
  stage_part<NF, 2>(0, NT, gA, gB, As, Bs, rA, colsw, K, wv);
  stage_part<NF, 3>(0, NT, gA, gB, As, Bs, rA, colsw, K, wv);
  stage_part<NF, 0>(1, NT, gA, gB, As, Bs, rA, colsw, K, wv);

  for (int t = 0; t < NT; ++t) {
    const int buf = t & 1;
    const u16* Ak0 = As + (buf * 2 + 0) * 8192 + wr * 4096 + rdoff;
    const u16* Ak1 = As + (buf * 2 + 1) * 8192 + wr * 4096 + rdoff;
    const u16* Bk0 = Bs + (buf * 2 + 0) * (BN * 32) + wc * (16 * NF) * 32 + rdoff;
    const u16* Bk1 = Bs + (buf * 2 + 1) * (BN * 32) + wc * (16 * NF) * 32 + rdoff;
    vbf16x8 afr[4], bfr[NF];

    // ---- phase 0: gate kh0, frags m0-3 x all n, kh0
    if (t < NT - 1) wait_vmcnt<V_MAIN>(); else wait_vmcnt<V_LAST>();
    __builtin_amdgcn_sched_barrier(0);
    __builtin_amdgcn_s_barrier();
    __builtin_amdgcn_sched_barrier(0);
#pragma unroll
    for (int n = 0; n < NF; ++n) bfr[n] = ldsv(Bk0 + n * 512);
#pragma unroll
    for (int i = 0; i < 4; ++i) afr[i] = ldsv(Ak0 + i * 512);
    stage_part<NF, 1>(t + 1, NT, gA, gB, As, Bs, rA, colsw, K, wv);
    __builtin_amdgcn_s_setprio(1);
#pragma unroll
    for (int i = 0; i < 4; ++i)
#pragma unroll
      for (int n = 0; n < NF; ++n)
        acc[i][n] = __builtin_amdgcn_mfma_f32_16x16x32_bf16(afr[i], bfr[n], acc[i][n], 0, 0, 0);
    __builtin_amdgcn_s_setprio(0);

    // ---- phase 1: frags m4-7, kh0
#pragma unroll
    for (int i = 0; i < 4; ++i) afr[i] = ldsv(Ak0 + (4 + i) * 512);
    stage_part<NF, 2>(t + 1, NT, gA, gB, As, Bs, rA, colsw, K, wv);
    __builtin_amdgcn_s_setprio(1);
#pragma unroll
    for (int i = 0; i < 4; ++i)
#pragma unroll
      for (int n = 0; n < NF; ++n)
        acc[4 + i][n] = __builtin_amdgcn_mfma_f32_16x16x32_bf16(afr[i], bfr[n], acc[4 + i][n], 0, 0, 0);
    __builtin_amdgcn_s_setprio(0);

    // ---- phase 2: gate kh1, frags m0-3, kh1
    if (t < NT - 1) wait_vmcnt<V_MAIN>(); else wait_vmcnt<0>();
    __builtin_amdgcn_sched_barrier(0);
    __builtin_amdgcn_s_barrier();
    __builtin_amdgcn_sched_barrier(0);
#pragma unroll
    for (int n = 0; n < NF; ++n) bfr[n] = ldsv(Bk1 + n * 512);
#pragma unroll
    for (int i = 0; i < 4; ++i) afr[i] = ldsv(Ak1 + i * 512);
    stage_part<NF, 3>(t + 1, NT, gA, gB, As, Bs, rA, colsw, K, wv);
    __builtin_amdgcn_s_setprio(1);
#pragma unroll
    for (int i = 0; i < 4; ++i)
#pragma unroll
      for (int n = 0; n < NF; ++n)
        acc[i][n] = __builtin_amdgcn_mfma_f32_16x16x32_bf16(afr[i], bfr[n], acc[i][n], 0, 0, 0);
    __builtin_amdgcn_s_setprio(0);

    // ---- phase 3: frags m4-7, kh1
#pragma unroll
    for (int i = 0; i < 4; ++i) afr[i] = ldsv(Ak1 + (4 + i) * 512);
    stage_part<NF, 0>(t + 2, NT, gA, gB, As, Bs, rA, colsw, K, wv);
    __builtin_amdgcn_s_setprio(1);
#pragma unroll
    for (int i = 0; i < 4; ++i)
#pragma unroll
      for (int n = 0; n < NF; ++n)
        acc[4 + i][n] = __builtin_amdgcn_mfma_f32_16x16x32_bf16(afr[i], bfr[n], acc[4 + i][n], 0, 0, 0);
    __builtin_amdgcn_s_setprio(0);
  }

  // ---- epilogue: C/D layout col=lane&15, row=(lane>>4)*4+r
  const long long zc = z * sC;
#pragma unroll
  for (int m = 0; m < 8; ++m) {
    const int row0 = brow + wr * 128 + m * 16 + (lane >> 4) * 4;
#pragma unroll
    for (int n = 0; n < NF; ++n) {
      const int col = bcol + wc * (16 * NF) + n * 16 + (lane & 15);
      const float bv = BIAS ? bias[col] : 0.0f;
#pragma unroll
      for (int r = 0; r < 4; ++r) {
        const float v = acc[m][n][r] + bv;
        const long long off = zc + (long long)(row0 + r) * N + col;
        if (OUTBF) ((u16*)Cout)[off] = f2bf(v);
        else       ((float*)Cout)[off] = v;
      }
    }
  }
}

// ---- row softmax in-place on bf16 [rows][2048]; one block per row
__global__ __launch_bounds__(256) void k_softmax(u16* __restrict__ P) {
  const long long row = blockIdx.x;
  u16* p = P + row * 2048;
  const int tid = threadIdx.x, lane = tid & 63, wv = tid >> 6;
  vbf16x8 v = ((const vbf16x8*)p)[tid];
  float f[8];
#pragma unroll
  for (int j = 0; j < 8; ++j) f[j] = bf2f((u16)v[j]);
  float m = f[0];
#pragma unroll
  for (int j = 1; j < 8; ++j) m = fmaxf(m, f[j]);
  for (int o = 1; o < 64; o <<= 1) m = fmaxf(m, __shfl_xor(m, o));
  __shared__ float redm[4], reds[4];
  if (lane == 0) redm[wv] = m;
  __syncthreads();
  m = fmaxf(fmaxf(redm[0], redm[1]), fmaxf(redm[2], redm[3]));
  float s = 0.0f;
#pragma unroll
  for (int j = 0; j < 8; ++j) { f[j] = __expf(f[j] - m); s += f[j]; }
  for (int o = 1; o < 64; o <<= 1) s += __shfl_xor(s, o);
  if (lane == 0) reds[wv] = s;
  __syncthreads();
  const float inv = 1.0f / (reds[0] + reds[1] + reds[2] + reds[3]);
#pragma unroll
  for (int j = 0; j < 8; ++j) v[j] = (short)f2bf(f[j] * inv);
  ((vbf16x8*)p)[tid] = v;
}

extern "C" void kernel_launch(void* const* d_in, const int* in_sizes, int n_in,
                              void* d_out, int out_size, void* d_ws, size_t ws_size,
                              hipStream_t stream) {
  const float* input = (const float*)d_in[0];   // [8][2048][512] f32
  const float* W     = (const float*)d_in[1];   // [512][512] f32
  const float* bias  = (const float*)d_in[2];   // [512] f32
  float* out = (float*)d_out;                   // [8][2048][512] f32

  char* ws = (char*)d_ws;
  u16* Xbf = (u16*)(ws);                        // 16 MiB
  u16* Vt  = (u16*)(ws + 16777216);             // 16 MiB
  u16* P   = (u16*)(ws + 2LL * 16777216);       // 64 MiB
  u16* Abf = (u16*)(ws + 2LL * 16777216);       // alias (first 16 MiB of P)
  u16* Wb  = (u16*)(ws + 3LL * 16777216);       // alias (0.5 MiB inside P)

  // 1) W -> bf16
  k_convw<<<256, 256, 0, stream>>>(W, Wb);
  // 2) input -> bf16 + transposed copy Vt[b][d][n]
  k_prep<<<dim3(32, 8, 8), 256, 0, stream>>>(input, Abf, Vt);
  // 3) X = input @ W^T + b   (16384x512x512) -> bf16   [256 wg, XCD-chunked brow]
  k_gemm8<2, true, true, 1><<<256, 512, 0, stream>>>(
      Abf, Wb, bias, Xbf, 16384, 512, 512, 0, 0, 0);
  // 4) S = X @ X^T per batch (2048x2048x512) -> bf16   [512 wg, 1 batch per XCD]
  k_gemm8<4, true, false, 0><<<512, 512, 0, stream>>>(
      Xbf, Xbf, nullptr, P, 2048, 2048, 512,
      2048LL * 512, 2048LL * 512, 2048LL * 2048);
  // 5) softmax rows in place
  k_softmax<<<16384, 256, 0, stream>>>(P);
  // 6) out = P @ Vt^T per batch (2048x512x2048) -> f32 [256 wg, 1 batch per XCD]
  k_gemm8<2, false, false, 2><<<256, 512, 0, stream>>>(
      P, Vt, nullptr, out, 2048, 512, 2048,
      2048LL * 2048, 512LL * 2048, 2048LL * 512);
}